// Round 9
// baseline (219.936 us; speedup 1.0000x reference)
//
#include <hip/hip_runtime.h>

// ---------- problem constants ----------
#define BATCH   2
#define SEQ     2048
#define DMODEL  1024
#define NHEAD   16
#define DKH     64
#define MTOT    (BATCH*SEQ)      // 4096 rows for the projection GEMMs
#define KDIM    DMODEL           // 1024 contraction for projections

// ws layout in bf16 elements (total 24M bf16 = 48 MB)
#define XB    0u                     // x bf16            [4096,1024]  4M
#define WQB   (4u*1024u*1024u)       // Wq bf16           [1024,1024]  1M
#define WKB   (5u*1024u*1024u)
#define WVB   (6u*1024u*1024u)
#define WOB   (7u*1024u*1024u)
#define QOFF  (8u*1024u*1024u)       // Q  [B,H,N,dk] (pre-scaled log2e/8) 4M
#define KOFF  (12u*1024u*1024u)      // K  [B,H,N,dk]                  4M
#define VOFF  (16u*1024u*1024u)      // V^T [B,H,dk,N]                 4M
#define OOFF  (20u*1024u*1024u)      // attn out, flat [B,N,D]         4M

typedef __bf16 bf16x8 __attribute__((ext_vector_type(8)));
typedef __bf16 bf16x4 __attribute__((ext_vector_type(4)));
typedef float  f32x4  __attribute__((ext_vector_type(4)));
typedef float  f32x16 __attribute__((ext_vector_type(16)));

// async global->LDS, 16B per lane; LDS dest is wave-uniform base (HW adds lane*16)
__device__ __forceinline__ void async16(const __bf16* g, __bf16* l) {
  __builtin_amdgcn_global_load_lds(
      (const __attribute__((address_space(1))) void*)g,
      (__attribute__((address_space(3))) void*)l, 16, 0, 0);
}

// ---------------------------------------------------------------------------
// fp32 -> bf16 conversion: blockIdx.y selects tensor (0:x, 1..4:Wq/Wk/Wv/Wo)
// ---------------------------------------------------------------------------
__global__ __launch_bounds__(256) void cvt_fp32_bf16(
    const float* __restrict__ x,  const float* __restrict__ wq,
    const float* __restrict__ wk, const float* __restrict__ wv,
    const float* __restrict__ wo, __bf16* __restrict__ ws)
{
  const float* src; __bf16* dst; int n;
  switch (blockIdx.y) {
    case 0:  src = x;  dst = ws + XB;  n = 4 * 1024 * 1024; break;
    case 1:  src = wq; dst = ws + WQB; n = 1024 * 1024;     break;
    case 2:  src = wk; dst = ws + WKB; n = 1024 * 1024;     break;
    case 3:  src = wv; dst = ws + WVB; n = 1024 * 1024;     break;
    default: src = wo; dst = ws + WOB; n = 1024 * 1024;     break;
  }
  const int i = (blockIdx.x * 256 + threadIdx.x) * 8;
  if (i < n) {
    const float4 a = *(const float4*)(src + i);
    const float4 b = *(const float4*)(src + i + 4);
    bf16x8 o;
    o[0] = (__bf16)a.x; o[1] = (__bf16)a.y; o[2] = (__bf16)a.z; o[3] = (__bf16)a.w;
    o[4] = (__bf16)b.x; o[5] = (__bf16)b.y; o[6] = (__bf16)b.z; o[7] = (__bf16)b.w;
    *(bf16x8*)(dst + i) = o;
  }
}

// ---------------------------------------------------------------------------
// 128x128 NT-GEMM core, BK=64 (16 K-iters instead of 32: halves the number
// of vmcnt(0)+barrier drains — the r8 audit showed the projections are
// drain-bound at K=1024, not store-bound).
// lds: A-tile [0,8192), B-tile [8192,16384) (32 KB). 8 chunks (64 bf16) per
// row, 16B-chunk XOR swizzle: chunk' = chunk ^ (row & 7).
// ---------------------------------------------------------------------------
__device__ __forceinline__ void gemm128_core(
    const __bf16* __restrict__ A, const __bf16* __restrict__ W,
    int m0, int n0, __bf16* lds, f32x4 (&acc)[4][4])
{
  __bf16* A_lds = lds;
  __bf16* B_lds = lds + 8192;
  const int t    = threadIdx.x;
  const int w    = t >> 6;
  const int lane = t & 63;
  const int ln15 = lane & 15;
  const int quad = lane >> 4;
  const int wr   = (w >> 1) << 6;   // wave row offset within 128
  const int wc   = (w & 1) << 6;    // wave col offset within 128

#pragma unroll
  for (int i = 0; i < 4; ++i)
#pragma unroll
    for (int j = 0; j < 4; ++j) acc[i][j] = (f32x4){0.f, 0.f, 0.f, 0.f};

  for (int kt = 0; kt < KDIM; kt += 64) {
    __syncthreads();   // previous tile's LDS reads done
#pragma unroll
    for (int issue = 0; issue < 4; ++issue) {
      const int cbase = issue * 256 + (w << 6);
      const int c     = cbase + lane;
      const int row   = c >> 3;                       // 8 chunks per row
      const int goff  = ((c & 7) ^ (row & 7)) << 3;   // swizzled source chunk
      async16(A + (size_t)(m0 + row) * KDIM + kt + goff, A_lds + cbase * 8);
      async16(W + (size_t)(n0 + row) * KDIM + kt + goff, B_lds + cbase * 8);
    }
    __syncthreads();   // vmcnt(0) drain: LDS tiles valid

#pragma unroll
    for (int sub = 0; sub < 2; ++sub) {
      bf16x8 af[4], bfr[4];
#pragma unroll
      for (int i = 0; i < 4; ++i) {
        const int row = wr + i * 16 + ln15;
        const int chunk = (4 * sub + quad) ^ (row & 7);
        af[i] = *(const bf16x8*)&A_lds[row * 64 + (chunk << 3)];
      }
#pragma unroll
      for (int j = 0; j < 4; ++j) {
        const int row = wc + j * 16 + ln15;
        const int chunk = (4 * sub + quad) ^ (row & 7);
        bfr[j] = *(const bf16x8*)&B_lds[row * 64 + (chunk << 3)];
      }
#pragma unroll
      for (int i = 0; i < 4; ++i)
#pragma unroll
        for (int j = 0; j < 4; ++j)
          acc[i][j] = __builtin_amdgcn_mfma_f32_16x16x32_bf16(af[i], bfr[j], acc[i][j], 0, 0, 0);
    }
  }
}

// ---------------------------------------------------------------------------
// Fused QKV projection: z=0 -> Q (scaled log2e/8) [B,H,N,dk]; z=1 -> K;
// z=2 -> V transposed [B,H,dk,N]. Biases fp32. 16B vectorized stores via
// per-wave LDS repack.
// ---------------------------------------------------------------------------
__global__ __launch_bounds__(256) void qkv_gemm(
    const __bf16* __restrict__ X,
    const __bf16* __restrict__ Wq, const float* __restrict__ bq,
    const __bf16* __restrict__ Wk, const float* __restrict__ bk,
    const __bf16* __restrict__ Wv, const float* __restrict__ bv,
    __bf16* __restrict__ ws)
{
  __shared__ __align__(16) __bf16 lds[128 * 128];   // 32 KB

  const int z = blockIdx.z;
  const __bf16* W    = (z == 0) ? Wq : (z == 1) ? Wk : Wv;
  const float*  bias = (z == 0) ? bq : (z == 1) ? bk : bv;
  __bf16* out = ws + ((z == 0) ? QOFF : (z == 1) ? KOFF : VOFF);
  // softmax runs in exp2 domain: fold 1/sqrt(dk) * log2(e) into Q
  const float scale = (z == 0) ? 0.125f * 1.44269504088896f : 1.0f;

  const int m0 = blockIdx.x * 128;
  const int n0 = blockIdx.y * 128;

  f32x4 acc[4][4];
  gemm128_core(X, W, m0, n0, lds, acc);

  const int t = threadIdx.x, w = t >> 6, lane = t & 63;
  const int ln15 = lane & 15, quad = lane >> 4;
  const int wr = (w >> 1) << 6, wc = (w & 1) << 6;

  // bias values for this wave's 64 columns (col = j*16+ln15)
  float bj4[4];
#pragma unroll
  for (int j = 0; j < 4; ++j) bj4[j] = bias[n0 + wc + j * 16 + ln15];

  __syncthreads();                     // all waves done reading K-tiles
  __bf16* scr = lds + (w << 10);       // per-wave 1024-elem scratch (2 KB)

  const int bb = m0 >> 11;             // batch (blocks never straddle)
  const int s_base = (m0 & 2047) + wr;
  const int h = (n0 + wc) >> 6;

  if (z != 2) {
    // ---- Q/K [B,H,N,dk]: row-major scratch [row16][d64], coalesced stores
    const int rdrow = lane & 15, rdseg = lane >> 4;
#pragma unroll
    for (int i = 0; i < 4; ++i) {
#pragma unroll
      for (int j = 0; j < 4; ++j)
#pragma unroll
        for (int rr = 0; rr < 4; ++rr)
          scr[(quad * 4 + rr) * 64 + j * 16 + ln15] =
              (__bf16)((acc[i][j][rr] + bj4[j]) * scale);
      // wave-private scratch: compiler orders via lgkmcnt, no barrier
      bf16x8 v0 = *(const bf16x8*)&scr[rdrow * 64 + rdseg * 16];
      bf16x8 v1 = *(const bf16x8*)&scr[rdrow * 64 + rdseg * 16 + 8];
      const int s = s_base + i * 16 + rdrow;
      __bf16* p = out + (((size_t)(bb * NHEAD + h)) * SEQ + s) * DKH + rdseg * 16;
      *(bf16x8*)p = v0;
      *(bf16x8*)&p[8] = v1;
    }
  } else {
    // ---- V^T [B,H,dk,N]: col-major scratch [d64][row16] does the transpose;
    // each lane then stores 32B contiguous in s.
#pragma unroll
    for (int i = 0; i < 4; ++i) {
#pragma unroll
      for (int j = 0; j < 4; ++j) {
        bf16x4 pk;
#pragma unroll
        for (int rr = 0; rr < 4; ++rr) pk[rr] = (__bf16)(acc[i][j][rr] + bj4[j]);
        *(bf16x4*)&scr[(j * 16 + ln15) * 16 + quad * 4] = pk;
      }
      bf16x8 c0 = *(const bf16x8*)&scr[lane * 16];
      bf16x8 c1 = *(const bf16x8*)&scr[lane * 16 + 8];
      __bf16* p = out + (((size_t)(bb * NHEAD + h)) * DKH + lane) * SEQ
                      + s_base + i * 16;
      *(bf16x8*)p = c0;
      *(bf16x8*)&p[8] = c1;
    }
  }
}

// ---------------------------------------------------------------------------
// Output projection: d_out(fp32) = O[M,K]bf16 @ Wo[N,K]bf16^T + bo(fp32).
// Epilogue: col-major fp32 scratch, f32x4 global stores (64B/lane coalesced).
// ---------------------------------------------------------------------------
__global__ __launch_bounds__(256) void out_gemm(
    const __bf16* __restrict__ A, const __bf16* __restrict__ Wo,
    const float* __restrict__ bo, float* __restrict__ out)
{
  __shared__ __align__(16) __bf16 lds[128 * 128];   // 32 KB

  const int m0 = blockIdx.x * 128;
  const int n0 = blockIdx.y * 128;

  f32x4 acc[4][4];
  gemm128_core(A, Wo, m0, n0, lds, acc);

  const int t = threadIdx.x, w = t >> 6, lane = t & 63;
  const int ln15 = lane & 15, quad = lane >> 4;
  const int wr = (w >> 1) << 6, wc = (w & 1) << 6;

  float bj4[4];
#pragma unroll
  for (int j = 0; j < 4; ++j) bj4[j] = bo[n0 + wc + j * 16 + ln15];

  __syncthreads();                        // all waves done reading K-tiles
  float* scr = (float*)lds + (w << 10);   // per-wave 1024-float scratch (4 KB)

  const int rdrow = lane & 15, rdseg = lane >> 4;
#pragma unroll
  for (int i = 0; i < 4; ++i) {
#pragma unroll
    for (int j = 0; j < 4; ++j) {
      f32x4 v;
#pragma unroll
      for (int rr = 0; rr < 4; ++rr) v[rr] = acc[i][j][rr] + bj4[j];
      *(f32x4*)&scr[(j * 16 + ln15) * 16 + quad * 4] = v;   // col-major
    }
    // read back one output-row segment (16 cols) per lane, store 4x f32x4
    const int m = m0 + wr + i * 16 + rdrow;
    float* p = out + (size_t)m * DMODEL + n0 + wc + rdseg * 16;
#pragma unroll
    for (int cc = 0; cc < 4; ++cc) {
      f32x4 v;
#pragma unroll
      for (int e = 0; e < 4; ++e)
        v[e] = scr[(rdseg * 16 + cc * 4 + e) * 16 + rdrow];
      *(f32x4*)&p[cc * 4] = v;
    }
  }
}

// ---------------------------------------------------------------------------
// Flash attention (r6 structure) + XCD-aware grid:
//   blockIdx.x = (b*NHEAD+h), blockIdx.y = q-tile  ->  linear id = bh + 32*q,
//   so all 32 q-tiles of one head map to the same XCD (linear % 8 == bh % 8):
//   4 heads/XCD x 512 KB K+V = 2 MB resident in the 4 MB per-XCD L2. r8's
//   FETCH_SIZE (70 MB vs 24 MB compulsory) showed staging was missing L2 and
//   eating ~900-cyc HBM latency in every barrier drain.
//  - 64-row Q tile, 128-thread blocks (2 waves x 32 q-rows), grid 1024.
//  - 32x32x16 MFMAs; bare v_exp_f32 exp2; single-buffer K/V staging
//    (r7: explicit dbuf regresses — compiler drains vmcnt before reads).
//  - SQ_LDS_BANK_CONFLICT ~7M is a wave64 b64/b128 multi-pass width
//    artifact, not true conflicts. Do not chase it.
// ---------------------------------------------------------------------------
__global__ __launch_bounds__(128) void attn_kernel(
    const __bf16* __restrict__ Qb, const __bf16* __restrict__ Kb,
    const __bf16* __restrict__ Vtb, __bf16* __restrict__ Ob)
{
  __shared__ __align__(16) __bf16 Qs[64 * 64];
  __shared__ __align__(16) __bf16 Ks[64 * 64];
  __shared__ __align__(16) __bf16 Vs[64 * 64];        // Vs[d][key]
  __shared__ __align__(16) __bf16 Ps[2 * 32 * 64];    // per-wave [32 q][64 key]

  const int t = threadIdx.x, w = t >> 6, lane = t & 63;
  const int ln31 = lane & 31, hl = lane >> 5;
  const int bh = blockIdx.x;                 // b*NHEAD + h  (XCD-locality key)
  const int q0 = blockIdx.y * 64;
  const int b = bh >> 4, h = bh & 15;

  const __bf16* Qg = Qb + (size_t)bh * SEQ * DKH + (size_t)q0 * DKH;
  const __bf16* Kg = Kb + (size_t)bh * SEQ * DKH;
  const __bf16* Vg = Vtb + (size_t)bh * DKH * SEQ;

  // stage Q tile (64x64), swizzled: 512 chunks / 128 threads = 4 rounds
#pragma unroll
  for (int issue = 0; issue < 4; ++issue) {
    const int cbase = issue * 128 + (w << 6);
    const int c = cbase + lane;
    const int row = c >> 3;                         // 8 chunks per 64-elem row
    const int goff = ((c & 7) ^ (row & 7)) << 3;
    async16(Qg + (size_t)row * DKH + goff, Qs + cbase * 8);
  }
  __syncthreads();

  // Q B-fragments for this wave's 32 q-rows (held in regs for whole kernel)
  const int qrow = (w << 5) + ln31;
  bf16x8 qf[4];
#pragma unroll
  for (int ks = 0; ks < 4; ++ks) {
    const int chunk = ((2 * ks + hl) ^ (qrow & 7));
    qf[ks] = *(const bf16x8*)&Qs[qrow * 64 + (chunk << 3)];
  }

  float l_lane = 0.f;          // row-sum for q-row `qrow` (lane-private)
  f32x16 o0, o1;               // O[32q][64d]: d-blocks 0/1; this lane: d=db*32+ln31
#pragma unroll
  for (int r = 0; r < 16; ++r) { o0[r] = 0.f; o1[r] = 0.f; }

  __bf16* Pw = Ps + w * (32 * 64);

  for (int kt = 0; kt < SEQ; kt += 64) {
    __syncthreads();   // prior iter's Ks/Vs reads complete
#pragma unroll
    for (int issue = 0; issue < 4; ++issue) {
      const int cbase = issue * 128 + (w << 6);
      const int c = cbase + lane;
      const int row = c >> 3;
      const int goff = ((c & 7) ^ (row & 7)) << 3;
      async16(Kg + (size_t)(kt + row) * DKH + goff, Ks + cbase * 8);
      async16(Vg + (size_t)row * SEQ + kt + goff, Vs + cbase * 8);
    }
    __syncthreads();   // drain

    // S^T = K Q^T: D[m=key][n=q]; 2 key-blocks of 32, K-dim 64 = 4 ksteps
    f32x16 s0, s1;
#pragma unroll
    for (int r = 0; r < 16; ++r) { s0[r] = 0.f; s1[r] = 0.f; }
#pragma unroll
    for (int ks = 0; ks < 4; ++ks) {
      const int r0 = ln31;            // key row, block 0
      const int r1 = 32 + ln31;       // key row, block 1
      const int c0 = (((2 * ks + hl) ^ (r0 & 7)) << 3);
      const int c1 = (((2 * ks + hl) ^ (r1 & 7)) << 3);
      bf16x8 kf0 = *(const bf16x8*)&Ks[r0 * 64 + c0];
      bf16x8 kf1 = *(const bf16x8*)&Ks[r1 * 64 + c1];
      s0 = __builtin_amdgcn_mfma_f32_32x32x16_bf16(kf0, qf[ks], s0, 0, 0, 0);
      s1 = __builtin_amdgcn_mfma_f32_32x32x16_bf16(kf1, qf[ks], s1, 0, 0, 0);
    }

    // p = 2^s (bare v_exp_f32); accumulate l; pack 4 keys -> b64 LDS writes.
    // reg r of key-block kb: key = kb*32 + (r&3) + 8*(r>>2) + 4*hl
    // P layout: [q=ln31][key], 16B granule g XOR-swizzled with (q&7).
#pragma unroll
    for (int kb = 0; kb < 2; ++kb) {
      const f32x16& s = kb ? s1 : s0;
#pragma unroll
      for (int rg = 0; rg < 4; ++rg) {
        bf16x4 pk;
#pragma unroll
        for (int rr = 0; rr < 4; ++rr) {
          const float pv = __builtin_amdgcn_exp2f(s[rg * 4 + rr]);
          l_lane += pv;
          pk[rr] = (__bf16)pv;
        }
        const int g = kb * 4 + rg;                        // 16B granule index
        *(bf16x4*)&Pw[ln31 * 64 + ((g ^ (ln31 & 7)) << 3) + hl * 4] = pk;
      }
    }
    // (no barrier: Pw is wave-private; compiler inserts lgkmcnt before reads)

    // O += P V: A=P[q][key] (swizzled read), B=Vs[d][key] rows as B-frags
#pragma unroll
    for (int ks = 0; ks < 4; ++ks) {
      const int pg = (2 * ks + hl) ^ (ln31 & 7);
      bf16x8 pf = *(const bf16x8*)&Pw[ln31 * 64 + (pg << 3)];
      const int v0 = ln31;            // d row, block 0
      const int v1 = 32 + ln31;       // d row, block 1
      const int c0 = (((2 * ks + hl) ^ (v0 & 7)) << 3);
      const int c1 = (((2 * ks + hl) ^ (v1 & 7)) << 3);
      bf16x8 vf0 = *(const bf16x8*)&Vs[v0 * 64 + c0];
      bf16x8 vf1 = *(const bf16x8*)&Vs[v1 * 64 + c1];
      o0 = __builtin_amdgcn_mfma_f32_32x32x16_bf16(pf, vf0, o0, 0, 0, 0);
      o1 = __builtin_amdgcn_mfma_f32_32x32x16_bf16(pf, vf1, o1, 0, 0, 0);
    }
  }

  // l: both half-waves hold partials of the same q-row -> one xor-32 add
  l_lane += __shfl_xor(l_lane, 32);
  const float inv = 1.0f / l_lane;   // inv for q-row `qrow`, held by this lane

  // epilogue: O[b, q, h*64+d]; lane = d col, q from regs; fetch inv via shfl
#pragma unroll
  for (int r = 0; r < 16; ++r) {
    const int qi = (r & 3) + 8 * (r >> 2) + 4 * hl;    // q within wave's 32
    const float iq = __shfl(inv, qi);                  // from lane qi (hl=0 half)
    const int q = q0 + (w << 5) + qi;
    __bf16* rowp = Ob + ((size_t)(b * SEQ + q)) * DMODEL + h * DKH;
    rowp[ln31]      = (__bf16)(o0[r] * iq);
    rowp[32 + ln31] = (__bf16)(o1[r] * iq);
  }
}

// ---------------------------------------------------------------------------
extern "C" void kernel_launch(void* const* d_in, const int* in_sizes, int n_in,
                              void* d_out, int out_size, void* d_ws, size_t ws_size,
                              hipStream_t stream)
{
  const float* x  = (const float*)d_in[0];
  const float* Wq = (const float*)d_in[1];
  const float* bq = (const float*)d_in[2];
  const float* Wk = (const float*)d_in[3];
  const float* bk = (const float*)d_in[4];
  const float* Wv = (const float*)d_in[5];
  const float* bv = (const float*)d_in[6];
  const float* Wo = (const float*)d_in[7];
  const float* bo = (const float*)d_in[8];
  float*  out = (float*)d_out;
  __bf16* ws  = (__bf16*)d_ws;

  // fp32 -> bf16 for x and the 4 weight matrices (one launch)
  cvt_fp32_bf16<<<dim3(2048, 5, 1), 256, 0, stream>>>(x, Wq, Wk, Wv, Wo, ws);

  // Q,K,V projections (fused, grid.z picks the matrix)
  qkv_gemm<<<dim3(MTOT / 128, DMODEL / 128, 3), 256, 0, stream>>>(
      ws + XB, ws + WQB, bq, ws + WKB, bk, ws + WVB, bv, ws);

  // flash attention: (bh, q-tile) — XCD-local K/V reuse
  attn_kernel<<<dim3(BATCH * NHEAD, SEQ / 64), 128, 0, stream>>>(
      ws + QOFF, ws + KOFF, ws + VOFF, ws + OOFF);

  // output projection -> fp32 d_out
  out_gemm<<<dim3(MTOT / 128, DMODEL / 128, 1), 256, 0, stream>>>(
      ws + OOFF, ws + WOB, bo, out);
}

// Round 10
// 192.794 us; speedup vs baseline: 1.1408x; 1.1408x over previous
//
#include <hip/hip_runtime.h>

// ---------- problem constants ----------
#define BATCH   2
#define SEQ     2048
#define DMODEL  1024
#define NHEAD   16
#define DKH     64
#define MTOT    (BATCH*SEQ)      // 4096 rows for the projection GEMMs
#define KDIM    DMODEL           // 1024 contraction for projections

// ws layout in bf16 elements (total 24M bf16 = 48 MB)
#define XB    0u                     // x bf16            [4096,1024]  4M
#define WQB   (4u*1024u*1024u)       // Wq bf16           [1024,1024]  1M
#define WKB   (5u*1024u*1024u)
#define WVB   (6u*1024u*1024u)
#define WOB   (7u*1024u*1024u)
#define QOFF  (8u*1024u*1024u)       // Q  [B,H,N,dk] (pre-scaled log2e/8) 4M
#define KOFF  (12u*1024u*1024u)      // K  [B,H,N,dk]                  4M
#define VOFF  (16u*1024u*1024u)      // V^T [B,H,dk,N]                 4M
#define OOFF  (20u*1024u*1024u)      // attn out, flat [B,N,D]         4M

typedef __bf16 bf16x8 __attribute__((ext_vector_type(8)));
typedef __bf16 bf16x4 __attribute__((ext_vector_type(4)));
typedef float  f32x4  __attribute__((ext_vector_type(4)));
typedef float  f32x16 __attribute__((ext_vector_type(16)));

// async global->LDS, 16B per lane; LDS dest is wave-uniform base (HW adds lane*16)
__device__ __forceinline__ void async16(const __bf16* g, __bf16* l) {
  __builtin_amdgcn_global_load_lds(
      (const __attribute__((address_space(1))) void*)g,
      (__attribute__((address_space(3))) void*)l, 16, 0, 0);
}

// ---------------------------------------------------------------------------
// fp32 -> bf16 conversion: blockIdx.y selects tensor (0:x, 1..4:Wq/Wk/Wv/Wo)
// ---------------------------------------------------------------------------
__global__ __launch_bounds__(256) void cvt_fp32_bf16(
    const float* __restrict__ x,  const float* __restrict__ wq,
    const float* __restrict__ wk, const float* __restrict__ wv,
    const float* __restrict__ wo, __bf16* __restrict__ ws)
{
  const float* src; __bf16* dst; int n;
  switch (blockIdx.y) {
    case 0:  src = x;  dst = ws + XB;  n = 4 * 1024 * 1024; break;
    case 1:  src = wq; dst = ws + WQB; n = 1024 * 1024;     break;
    case 2:  src = wk; dst = ws + WKB; n = 1024 * 1024;     break;
    case 3:  src = wv; dst = ws + WVB; n = 1024 * 1024;     break;
    default: src = wo; dst = ws + WOB; n = 1024 * 1024;     break;
  }
  const int i = (blockIdx.x * 256 + threadIdx.x) * 8;
  if (i < n) {
    const float4 a = *(const float4*)(src + i);
    const float4 b = *(const float4*)(src + i + 4);
    bf16x8 o;
    o[0] = (__bf16)a.x; o[1] = (__bf16)a.y; o[2] = (__bf16)a.z; o[3] = (__bf16)a.w;
    o[4] = (__bf16)b.x; o[5] = (__bf16)b.y; o[6] = (__bf16)b.z; o[7] = (__bf16)b.w;
    *(bf16x8*)(dst + i) = o;
  }
}

// ---------------------------------------------------------------------------
// 128x128 NT-GEMM core, BK=32 (r8 version — BK=64 regressed, r9 lesson).
// lds: A-tile [0,4096), B-tile [4096,8192) (16 KB).
// 16B-chunk XOR swizzle: chunk' = chunk ^ (row & 3).
// ---------------------------------------------------------------------------
__device__ __forceinline__ void gemm128_core(
    const __bf16* __restrict__ A, const __bf16* __restrict__ W,
    int m0, int n0, __bf16* lds, f32x4 (&acc)[4][4])
{
  __bf16* A_lds = lds;
  __bf16* B_lds = lds + 4096;
  const int t    = threadIdx.x;
  const int w    = t >> 6;
  const int lane = t & 63;
  const int ln15 = lane & 15;
  const int quad = lane >> 4;
  const int wr   = (w >> 1) << 6;   // wave row offset within 128
  const int wc   = (w & 1) << 6;    // wave col offset within 128

#pragma unroll
  for (int i = 0; i < 4; ++i)
#pragma unroll
    for (int j = 0; j < 4; ++j) acc[i][j] = (f32x4){0.f, 0.f, 0.f, 0.f};

  for (int kt = 0; kt < KDIM; kt += 32) {
    __syncthreads();   // previous tile's LDS reads done
#pragma unroll
    for (int issue = 0; issue < 2; ++issue) {
      const int cbase = issue * 256 + (w << 6);
      const int c     = cbase + lane;
      const int row   = c >> 2;                       // 4 chunks (32 bf16) per row
      const int goff  = ((c & 3) ^ (row & 3)) << 3;   // swizzled source chunk
      async16(A + (size_t)(m0 + row) * KDIM + kt + goff, A_lds + cbase * 8);
      async16(W + (size_t)(n0 + row) * KDIM + kt + goff, B_lds + cbase * 8);
    }
    __syncthreads();   // vmcnt(0) drain: LDS tiles valid

    bf16x8 af[4], bfr[4];
#pragma unroll
    for (int i = 0; i < 4; ++i) {
      const int row = wr + i * 16 + ln15;
      af[i] = *(const bf16x8*)&A_lds[row * 32 + ((quad ^ (row & 3)) << 3)];
    }
#pragma unroll
    for (int j = 0; j < 4; ++j) {
      const int row = wc + j * 16 + ln15;
      bfr[j] = *(const bf16x8*)&B_lds[row * 32 + ((quad ^ (row & 3)) << 3)];
    }
#pragma unroll
    for (int i = 0; i < 4; ++i)
#pragma unroll
      for (int j = 0; j < 4; ++j)
        acc[i][j] = __builtin_amdgcn_mfma_f32_16x16x32_bf16(af[i], bfr[j], acc[i][j], 0, 0, 0);
  }
}

// ---------------------------------------------------------------------------
// Fused QKV projection: z=0 -> Q (scaled log2e/8) [B,H,N,dk]; z=1 -> K;
// z=2 -> V transposed [B,H,dk,N]. Biases fp32. 16B vectorized stores via
// per-wave LDS repack.
// ---------------------------------------------------------------------------
__global__ __launch_bounds__(256) void qkv_gemm(
    const __bf16* __restrict__ X,
    const __bf16* __restrict__ Wq, const float* __restrict__ bq,
    const __bf16* __restrict__ Wk, const float* __restrict__ bk,
    const __bf16* __restrict__ Wv, const float* __restrict__ bv,
    __bf16* __restrict__ ws)
{
  __shared__ __align__(16) __bf16 lds[128 * 64];   // 16 KB

  const int z = blockIdx.z;
  const __bf16* W    = (z == 0) ? Wq : (z == 1) ? Wk : Wv;
  const float*  bias = (z == 0) ? bq : (z == 1) ? bk : bv;
  __bf16* out = ws + ((z == 0) ? QOFF : (z == 1) ? KOFF : VOFF);
  // softmax runs in exp2 domain: fold 1/sqrt(dk) * log2(e) into Q
  const float scale = (z == 0) ? 0.125f * 1.44269504088896f : 1.0f;

  const int m0 = blockIdx.x * 128;
  const int n0 = blockIdx.y * 128;

  f32x4 acc[4][4];
  gemm128_core(X, W, m0, n0, lds, acc);

  const int t = threadIdx.x, w = t >> 6, lane = t & 63;
  const int ln15 = lane & 15, quad = lane >> 4;
  const int wr = (w >> 1) << 6, wc = (w & 1) << 6;

  // bias values for this wave's 64 columns (col = j*16+ln15)
  float bj4[4];
#pragma unroll
  for (int j = 0; j < 4; ++j) bj4[j] = bias[n0 + wc + j * 16 + ln15];

  __syncthreads();                     // all waves done reading K-tiles
  __bf16* scr = lds + (w << 10);       // per-wave 1024-elem scratch (2 KB)

  const int bb = m0 >> 11;             // batch (blocks never straddle)
  const int s_base = (m0 & 2047) + wr;
  const int h = (n0 + wc) >> 6;

  if (z != 2) {
    // ---- Q/K [B,H,N,dk]: row-major scratch [row16][d64], coalesced stores
    const int rdrow = lane & 15, rdseg = lane >> 4;
#pragma unroll
    for (int i = 0; i < 4; ++i) {
#pragma unroll
      for (int j = 0; j < 4; ++j)
#pragma unroll
        for (int rr = 0; rr < 4; ++rr)
          scr[(quad * 4 + rr) * 64 + j * 16 + ln15] =
              (__bf16)((acc[i][j][rr] + bj4[j]) * scale);
      // wave-private scratch: compiler orders via lgkmcnt, no barrier
      bf16x8 v0 = *(const bf16x8*)&scr[rdrow * 64 + rdseg * 16];
      bf16x8 v1 = *(const bf16x8*)&scr[rdrow * 64 + rdseg * 16 + 8];
      const int s = s_base + i * 16 + rdrow;
      __bf16* p = out + (((size_t)(bb * NHEAD + h)) * SEQ + s) * DKH + rdseg * 16;
      *(bf16x8*)p = v0;
      *(bf16x8*)&p[8] = v1;
    }
  } else {
    // ---- V^T [B,H,dk,N]: col-major scratch [d64][row16] does the transpose;
    // each lane then stores 32B contiguous in s.
#pragma unroll
    for (int i = 0; i < 4; ++i) {
#pragma unroll
      for (int j = 0; j < 4; ++j) {
        bf16x4 pk;
#pragma unroll
        for (int rr = 0; rr < 4; ++rr) pk[rr] = (__bf16)(acc[i][j][rr] + bj4[j]);
        *(bf16x4*)&scr[(j * 16 + ln15) * 16 + quad * 4] = pk;
      }
      bf16x8 c0 = *(const bf16x8*)&scr[lane * 16];
      bf16x8 c1 = *(const bf16x8*)&scr[lane * 16 + 8];
      __bf16* p = out + (((size_t)(bb * NHEAD + h)) * DKH + lane) * SEQ
                      + s_base + i * 16;
      *(bf16x8*)p = c0;
      *(bf16x8*)&p[8] = c1;
    }
  }
}

// ---------------------------------------------------------------------------
// Output projection: d_out(fp32) = O[M,K]bf16 @ Wo[N,K]bf16^T + bo(fp32).
// 64x128 tile -> 512 blocks (2/CU; r8's 128x128 had 1 block/CU and the full
// 32-iteration drain chain exposed). 4 waves, each 64 rows x 32 cols.
// ---------------------------------------------------------------------------
__global__ __launch_bounds__(256) void out_gemm(
    const __bf16* __restrict__ A, const __bf16* __restrict__ Wo,
    const float* __restrict__ bo, float* __restrict__ out)
{
  __shared__ __align__(16) __bf16 lds[6144];   // A 64x32 | B 128x32 (12 KB)
  __bf16* A_lds = lds;
  __bf16* B_lds = lds + 2048;

  const int m0 = blockIdx.x * 64;
  const int n0 = blockIdx.y * 128;

  const int t = threadIdx.x, w = t >> 6, lane = t & 63;
  const int ln15 = lane & 15, quad = lane >> 4;

  f32x4 acc[4][2];
#pragma unroll
  for (int i = 0; i < 4; ++i)
#pragma unroll
    for (int j = 0; j < 2; ++j) acc[i][j] = (f32x4){0.f, 0.f, 0.f, 0.f};

  for (int kt = 0; kt < KDIM; kt += 32) {
    __syncthreads();
    {  // A: 64 rows x 4 chunks = 256 chunks = 1 issue
      const int c = (w << 6) + lane;
      const int row = c >> 2;
      const int goff = ((c & 3) ^ (row & 3)) << 3;
      async16(A + (size_t)(m0 + row) * KDIM + kt + goff, A_lds + c * 8);
    }
#pragma unroll
    for (int issue = 0; issue < 2; ++issue) {  // B: 128 rows x 4 chunks = 2 issues
      const int cbase = issue * 256 + (w << 6);
      const int c = cbase + lane;
      const int row = c >> 2;
      const int goff = ((c & 3) ^ (row & 3)) << 3;
      async16(Wo + (size_t)(n0 + row) * KDIM + kt + goff, B_lds + cbase * 8);
    }
    __syncthreads();

    bf16x8 af[4], bfr[2];
#pragma unroll
    for (int i = 0; i < 4; ++i) {
      const int row = i * 16 + ln15;
      af[i] = *(const bf16x8*)&A_lds[row * 32 + ((quad ^ (row & 3)) << 3)];
    }
#pragma unroll
    for (int j = 0; j < 2; ++j) {
      const int row = (w << 5) + j * 16 + ln15;
      bfr[j] = *(const bf16x8*)&B_lds[row * 32 + ((quad ^ (row & 3)) << 3)];
    }
#pragma unroll
    for (int i = 0; i < 4; ++i)
#pragma unroll
      for (int j = 0; j < 2; ++j)
        acc[i][j] = __builtin_amdgcn_mfma_f32_16x16x32_bf16(af[i], bfr[j], acc[i][j], 0, 0, 0);
  }

  float bj2[2];
#pragma unroll
  for (int j = 0; j < 2; ++j) bj2[j] = bo[n0 + (w << 5) + j * 16 + ln15];

  __syncthreads();                          // waves done reading A/B tiles
  float* scrf = (float*)lds + (w << 9);     // per-wave 512-float scratch (2 KB)

  const int rdrow = lane & 15, rdseg = lane >> 4;
#pragma unroll
  for (int i = 0; i < 4; ++i) {
#pragma unroll
    for (int j = 0; j < 2; ++j) {
      f32x4 v;
#pragma unroll
      for (int rr = 0; rr < 4; ++rr) v[rr] = acc[i][j][rr] + bj2[j];
      *(f32x4*)&scrf[(j * 16 + ln15) * 16 + quad * 4] = v;   // col-major
    }
    const int m = m0 + i * 16 + rdrow;
    float* p = out + (size_t)m * DMODEL + n0 + (w << 5) + rdseg * 8;
#pragma unroll
    for (int cc = 0; cc < 2; ++cc) {
      f32x4 v;
#pragma unroll
      for (int e = 0; e < 4; ++e)
        v[e] = scrf[(rdseg * 8 + cc * 4 + e) * 16 + rdrow];
      *(f32x4*)&p[cc * 4] = v;
    }
  }
}

// ---------------------------------------------------------------------------
// Flash attention — 128 q-rows/block, 4 waves (256 thr), 512 blocks.
// Per-wave code identical to the verified r6/r9 path (32 q-rows/wave,
// 32x32x16 MFMAs, bare exp2, stride-64 XOR P buffer); doubling q-rows per
// staged K/V tile HALVES total staging DMAs, vmcnt drains and barriers per
// FLOP. Staging is XCD-local L2 (r9: FETCH 70->12 MB via bh-major grid).
//  - r7 lesson: explicit K/V dbuf regresses (compiler drains vmcnt early).
//  - SQ_LDS_BANK_CONFLICT ~7M = wave64 b64/b128 multi-pass artifact; ignore.
// ---------------------------------------------------------------------------
__global__ __launch_bounds__(256) void attn_kernel(
    const __bf16* __restrict__ Qb, const __bf16* __restrict__ Kb,
    const __bf16* __restrict__ Vtb, __bf16* __restrict__ Ob)
{
  __shared__ __align__(16) __bf16 Qs[128 * 64];       // 16 KB
  __shared__ __align__(16) __bf16 Ks[64 * 64];        // 8 KB
  __shared__ __align__(16) __bf16 Vs[64 * 64];        // 8 KB, Vs[d][key]
  __shared__ __align__(16) __bf16 Ps[4 * 32 * 64];    // 16 KB, per-wave P

  const int t = threadIdx.x, w = t >> 6, lane = t & 63;
  const int ln31 = lane & 31, hl = lane >> 5;
  const int bh = blockIdx.x;                 // b*NHEAD + h  (XCD-locality key)
  const int q0 = blockIdx.y * 128;
  const int b = bh >> 4, h = bh & 15;

  const __bf16* Qg = Qb + (size_t)bh * SEQ * DKH + (size_t)q0 * DKH;
  const __bf16* Kg = Kb + (size_t)bh * SEQ * DKH;
  const __bf16* Vg = Vtb + (size_t)bh * DKH * SEQ;

  // stage Q tile (128x64): 1024 chunks / 256 threads = 4 issues
#pragma unroll
  for (int issue = 0; issue < 4; ++issue) {
    const int cbase = issue * 256 + (w << 6);
    const int c = cbase + lane;
    const int row = c >> 3;                         // 8 chunks per 64-elem row
    const int goff = ((c & 7) ^ (row & 7)) << 3;
    async16(Qg + (size_t)row * DKH + goff, Qs + cbase * 8);
  }
  __syncthreads();

  // Q B-fragments for this wave's 32 q-rows (held in regs for whole kernel)
  const int qrow = (w << 5) + ln31;
  bf16x8 qf[4];
#pragma unroll
  for (int ks = 0; ks < 4; ++ks) {
    const int chunk = ((2 * ks + hl) ^ (qrow & 7));
    qf[ks] = *(const bf16x8*)&Qs[qrow * 64 + (chunk << 3)];
  }

  float l_lane = 0.f;          // row-sum for q-row `qrow` (lane-private)
  f32x16 o0, o1;               // O[32q][64d]: d-blocks 0/1; this lane: d=db*32+ln31
#pragma unroll
  for (int r = 0; r < 16; ++r) { o0[r] = 0.f; o1[r] = 0.f; }

  __bf16* Pw = Ps + w * (32 * 64);

  for (int kt = 0; kt < SEQ; kt += 64) {
    __syncthreads();   // prior iter's Ks/Vs reads complete
#pragma unroll
    for (int issue = 0; issue < 2; ++issue) {   // K,V: 512 chunks each
      const int cbase = issue * 256 + (w << 6);
      const int c = cbase + lane;
      const int row = c >> 3;
      const int goff = ((c & 7) ^ (row & 7)) << 3;
      async16(Kg + (size_t)(kt + row) * DKH + goff, Ks + cbase * 8);
      async16(Vg + (size_t)row * SEQ + kt + goff, Vs + cbase * 8);
    }
    __syncthreads();   // drain

    // S^T = K Q^T: D[m=key][n=q]; 2 key-blocks of 32, K-dim 64 = 4 ksteps
    f32x16 s0, s1;
#pragma unroll
    for (int r = 0; r < 16; ++r) { s0[r] = 0.f; s1[r] = 0.f; }
#pragma unroll
    for (int ks = 0; ks < 4; ++ks) {
      const int r0 = ln31;            // key row, block 0
      const int r1 = 32 + ln31;       // key row, block 1
      const int c0 = (((2 * ks + hl) ^ (r0 & 7)) << 3);
      const int c1 = (((2 * ks + hl) ^ (r1 & 7)) << 3);
      bf16x8 kf0 = *(const bf16x8*)&Ks[r0 * 64 + c0];
      bf16x8 kf1 = *(const bf16x8*)&Ks[r1 * 64 + c1];
      s0 = __builtin_amdgcn_mfma_f32_32x32x16_bf16(kf0, qf[ks], s0, 0, 0, 0);
      s1 = __builtin_amdgcn_mfma_f32_32x32x16_bf16(kf1, qf[ks], s1, 0, 0, 0);
    }

    // p = 2^s (bare v_exp_f32); accumulate l; pack 4 keys -> b64 LDS writes.
    // reg r of key-block kb: key = kb*32 + (r&3) + 8*(r>>2) + 4*hl
    // P layout: [q=ln31][key], 16B granule g XOR-swizzled with (q&7).
#pragma unroll
    for (int kb = 0; kb < 2; ++kb) {
      const f32x16& s = kb ? s1 : s0;
#pragma unroll
      for (int rg = 0; rg < 4; ++rg) {
        bf16x4 pk;
#pragma unroll
        for (int rr = 0; rr < 4; ++rr) {
          const float pv = __builtin_amdgcn_exp2f(s[rg * 4 + rr]);
          l_lane += pv;
          pk[rr] = (__bf16)pv;
        }
        const int g = kb * 4 + rg;                        // 16B granule index
        *(bf16x4*)&Pw[ln31 * 64 + ((g ^ (ln31 & 7)) << 3) + hl * 4] = pk;
      }
    }
    // (no barrier: Pw is wave-private; compiler inserts lgkmcnt before reads)

    // O += P V: A=P[q][key] (swizzled read), B=Vs[d][key] rows as B-frags
#pragma unroll
    for (int ks = 0; ks < 4; ++ks) {
      const int pg = (2 * ks + hl) ^ (ln31 & 7);
      bf16x8 pf = *(const bf16x8*)&Pw[ln31 * 64 + (pg << 3)];
      const int v0 = ln31;            // d row, block 0
      const int v1 = 32 + ln31;       // d row, block 1
      const int c0 = (((2 * ks + hl) ^ (v0 & 7)) << 3);
      const int c1 = (((2 * ks + hl) ^ (v1 & 7)) << 3);
      bf16x8 vf0 = *(const bf16x8*)&Vs[v0 * 64 + c0];
      bf16x8 vf1 = *(const bf16x8*)&Vs[v1 * 64 + c1];
      o0 = __builtin_amdgcn_mfma_f32_32x32x16_bf16(pf, vf0, o0, 0, 0, 0);
      o1 = __builtin_amdgcn_mfma_f32_32x32x16_bf16(pf, vf1, o1, 0, 0, 0);
    }
  }

  // l: both half-waves hold partials of the same q-row -> one xor-32 add
  l_lane += __shfl_xor(l_lane, 32);
  const float inv = 1.0f / l_lane;   // inv for q-row `qrow`, held by this lane

  // epilogue: O[b, q, h*64+d]; lane = d col, q from regs; fetch inv via shfl
#pragma unroll
  for (int r = 0; r < 16; ++r) {
    const int qi = (r & 3) + 8 * (r >> 2) + 4 * hl;    // q within wave's 32
    const float iq = __shfl(inv, qi);                  // from lane qi (hl=0 half)
    const int q = q0 + (w << 5) + qi;
    __bf16* rowp = Ob + ((size_t)(b * SEQ + q)) * DMODEL + h * DKH;
    rowp[ln31]      = (__bf16)(o0[r] * iq);
    rowp[32 + ln31] = (__bf16)(o1[r] * iq);
  }
}

// ---------------------------------------------------------------------------
extern "C" void kernel_launch(void* const* d_in, const int* in_sizes, int n_in,
                              void* d_out, int out_size, void* d_ws, size_t ws_size,
                              hipStream_t stream)
{
  const float* x  = (const float*)d_in[0];
  const float* Wq = (const float*)d_in[1];
  const float* bq = (const float*)d_in[2];
  const float* Wk = (const float*)d_in[3];
  const float* bk = (const float*)d_in[4];
  const float* Wv = (const float*)d_in[5];
  const float* bv = (const float*)d_in[6];
  const float* Wo = (const float*)d_in[7];
  const float* bo = (const float*)d_in[8];
  float*  out = (float*)d_out;
  __bf16* ws  = (__bf16*)d_ws;

  // fp32 -> bf16 for x and the 4 weight matrices (one launch)
  cvt_fp32_bf16<<<dim3(2048, 5, 1), 256, 0, stream>>>(x, Wq, Wk, Wv, Wo, ws);

  // Q,K,V projections (fused, grid.z picks the matrix)
  qkv_gemm<<<dim3(MTOT / 128, DMODEL / 128, 3), 256, 0, stream>>>(
      ws + XB, ws + WQB, bq, ws + WKB, bk, ws + WVB, bv, ws);

  // flash attention: (bh, q-tile of 128) = 512 blocks x 256 threads
  attn_kernel<<<dim3(BATCH * NHEAD, SEQ / 128), 256, 0, stream>>>(
      ws + QOFF, ws + KOFF, ws + VOFF, ws + OOFF);

  // output projection -> fp32 d_out (64x128 tiles, 512 blocks)
  out_gemm<<<dim3(MTOT / 64, DMODEL / 128), 256, 0, stream>>>(
      ws + OOFF, ws + WOB, bo, out);
}

// Round 11
// 192.232 us; speedup vs baseline: 1.1441x; 1.0029x over previous
//
#include <hip/hip_runtime.h>

// ---------- problem constants ----------
#define BATCH   2
#define SEQ     2048
#define DMODEL  1024
#define NHEAD   16
#define DKH     64
#define MTOT    (BATCH*SEQ)      // 4096 rows for the projection GEMMs
#define KDIM    DMODEL           // 1024 contraction for projections

// ws layout in bf16 elements (total 24M bf16 = 48 MB)
#define XB    0u                     // x bf16            [4096,1024]  4M
#define WQB   (4u*1024u*1024u)       // Wq bf16           [1024,1024]  1M
#define WKB   (5u*1024u*1024u)
#define WVB   (6u*1024u*1024u)
#define WOB   (7u*1024u*1024u)
#define QOFF  (8u*1024u*1024u)       // Q  [B,H,N,dk] (pre-scaled log2e/8) 4M
#define KOFF  (12u*1024u*1024u)      // K  [B,H,N,dk]                  4M
#define VOFF  (16u*1024u*1024u)      // V^T [B,H,dk,N]                 4M
#define OOFF  (20u*1024u*1024u)      // attn out, flat [B,N,D]         4M

typedef __bf16 bf16x8 __attribute__((ext_vector_type(8)));
typedef __bf16 bf16x4 __attribute__((ext_vector_type(4)));
typedef float  f32x4  __attribute__((ext_vector_type(4)));
typedef float  f32x16 __attribute__((ext_vector_type(16)));

// async global->LDS, 16B per lane; LDS dest is wave-uniform base (HW adds lane*16)
__device__ __forceinline__ void async16(const __bf16* g, __bf16* l) {
  __builtin_amdgcn_global_load_lds(
      (const __attribute__((address_space(1))) void*)g,
      (__attribute__((address_space(3))) void*)l, 16, 0, 0);
}

// ---------------------------------------------------------------------------
// fp32 -> bf16 conversion: blockIdx.y selects tensor (0:x, 1..4:Wq/Wk/Wv/Wo)
// ---------------------------------------------------------------------------
__global__ __launch_bounds__(256) void cvt_fp32_bf16(
    const float* __restrict__ x,  const float* __restrict__ wq,
    const float* __restrict__ wk, const float* __restrict__ wv,
    const float* __restrict__ wo, __bf16* __restrict__ ws)
{
  const float* src; __bf16* dst; int n;
  switch (blockIdx.y) {
    case 0:  src = x;  dst = ws + XB;  n = 4 * 1024 * 1024; break;
    case 1:  src = wq; dst = ws + WQB; n = 1024 * 1024;     break;
    case 2:  src = wk; dst = ws + WKB; n = 1024 * 1024;     break;
    case 3:  src = wv; dst = ws + WVB; n = 1024 * 1024;     break;
    default: src = wo; dst = ws + WOB; n = 1024 * 1024;     break;
  }
  const int i = (blockIdx.x * 256 + threadIdx.x) * 8;
  if (i < n) {
    const float4 a = *(const float4*)(src + i);
    const float4 b = *(const float4*)(src + i + 4);
    bf16x8 o;
    o[0] = (__bf16)a.x; o[1] = (__bf16)a.y; o[2] = (__bf16)a.z; o[3] = (__bf16)a.w;
    o[4] = (__bf16)b.x; o[5] = (__bf16)b.y; o[6] = (__bf16)b.z; o[7] = (__bf16)b.w;
    *(bf16x8*)(dst + i) = o;
  }
}

// ---------------------------------------------------------------------------
// 128x128 NT-GEMM core, BK=32 (r8 version — BK=64 regressed, r9 lesson).
// lds: A-tile [0,4096), B-tile [4096,8192) (16 KB).
// 16B-chunk XOR swizzle: chunk' = chunk ^ (row & 3).
// ---------------------------------------------------------------------------
__device__ __forceinline__ void gemm128_core(
    const __bf16* __restrict__ A, const __bf16* __restrict__ W,
    int m0, int n0, __bf16* lds, f32x4 (&acc)[4][4])
{
  __bf16* A_lds = lds;
  __bf16* B_lds = lds + 4096;
  const int t    = threadIdx.x;
  const int w    = t >> 6;
  const int lane = t & 63;
  const int ln15 = lane & 15;
  const int quad = lane >> 4;
  const int wr   = (w >> 1) << 6;   // wave row offset within 128
  const int wc   = (w & 1) << 6;    // wave col offset within 128

#pragma unroll
  for (int i = 0; i < 4; ++i)
#pragma unroll
    for (int j = 0; j < 4; ++j) acc[i][j] = (f32x4){0.f, 0.f, 0.f, 0.f};

  for (int kt = 0; kt < KDIM; kt += 32) {
    __syncthreads();   // previous tile's LDS reads done
#pragma unroll
    for (int issue = 0; issue < 2; ++issue) {
      const int cbase = issue * 256 + (w << 6);
      const int c     = cbase + lane;
      const int row   = c >> 2;                       // 4 chunks (32 bf16) per row
      const int goff  = ((c & 3) ^ (row & 3)) << 3;   // swizzled source chunk
      async16(A + (size_t)(m0 + row) * KDIM + kt + goff, A_lds + cbase * 8);
      async16(W + (size_t)(n0 + row) * KDIM + kt + goff, B_lds + cbase * 8);
    }
    __syncthreads();   // vmcnt(0) drain: LDS tiles valid

    bf16x8 af[4], bfr[4];
#pragma unroll
    for (int i = 0; i < 4; ++i) {
      const int row = wr + i * 16 + ln15;
      af[i] = *(const bf16x8*)&A_lds[row * 32 + ((quad ^ (row & 3)) << 3)];
    }
#pragma unroll
    for (int j = 0; j < 4; ++j) {
      const int row = wc + j * 16 + ln15;
      bfr[j] = *(const bf16x8*)&B_lds[row * 32 + ((quad ^ (row & 3)) << 3)];
    }
#pragma unroll
    for (int i = 0; i < 4; ++i)
#pragma unroll
      for (int j = 0; j < 4; ++j)
        acc[i][j] = __builtin_amdgcn_mfma_f32_16x16x32_bf16(af[i], bfr[j], acc[i][j], 0, 0, 0);
  }
}

// ---------------------------------------------------------------------------
// Fused QKV projection: z=0 -> Q (scaled log2e/8) [B,H,N,dk]; z=1 -> K;
// z=2 -> V transposed [B,H,dk,N]. Biases fp32. 16B vectorized stores via
// per-wave LDS repack.
// ---------------------------------------------------------------------------
__global__ __launch_bounds__(256) void qkv_gemm(
    const __bf16* __restrict__ X,
    const __bf16* __restrict__ Wq, const float* __restrict__ bq,
    const __bf16* __restrict__ Wk, const float* __restrict__ bk,
    const __bf16* __restrict__ Wv, const float* __restrict__ bv,
    __bf16* __restrict__ ws)
{
  __shared__ __align__(16) __bf16 lds[128 * 64];   // 16 KB

  const int z = blockIdx.z;
  const __bf16* W    = (z == 0) ? Wq : (z == 1) ? Wk : Wv;
  const float*  bias = (z == 0) ? bq : (z == 1) ? bk : bv;
  __bf16* out = ws + ((z == 0) ? QOFF : (z == 1) ? KOFF : VOFF);
  // softmax runs in exp2 domain: fold 1/sqrt(dk) * log2(e) into Q
  const float scale = (z == 0) ? 0.125f * 1.44269504088896f : 1.0f;

  const int m0 = blockIdx.x * 128;
  const int n0 = blockIdx.y * 128;

  f32x4 acc[4][4];
  gemm128_core(X, W, m0, n0, lds, acc);

  const int t = threadIdx.x, w = t >> 6, lane = t & 63;
  const int ln15 = lane & 15, quad = lane >> 4;
  const int wr = (w >> 1) << 6, wc = (w & 1) << 6;

  // bias values for this wave's 64 columns (col = j*16+ln15)
  float bj4[4];
#pragma unroll
  for (int j = 0; j < 4; ++j) bj4[j] = bias[n0 + wc + j * 16 + ln15];

  __syncthreads();                     // all waves done reading K-tiles
  __bf16* scr = lds + (w << 10);       // per-wave 1024-elem scratch (2 KB)

  const int bb = m0 >> 11;             // batch (blocks never straddle)
  const int s_base = (m0 & 2047) + wr;
  const int h = (n0 + wc) >> 6;

  if (z != 2) {
    // ---- Q/K [B,H,N,dk]: row-major scratch [row16][d64], coalesced stores
    const int rdrow = lane & 15, rdseg = lane >> 4;
#pragma unroll
    for (int i = 0; i < 4; ++i) {
#pragma unroll
      for (int j = 0; j < 4; ++j)
#pragma unroll
        for (int rr = 0; rr < 4; ++rr)
          scr[(quad * 4 + rr) * 64 + j * 16 + ln15] =
              (__bf16)((acc[i][j][rr] + bj4[j]) * scale);
      // wave-private scratch: compiler orders via lgkmcnt, no barrier
      bf16x8 v0 = *(const bf16x8*)&scr[rdrow * 64 + rdseg * 16];
      bf16x8 v1 = *(const bf16x8*)&scr[rdrow * 64 + rdseg * 16 + 8];
      const int s = s_base + i * 16 + rdrow;
      __bf16* p = out + (((size_t)(bb * NHEAD + h)) * SEQ + s) * DKH + rdseg * 16;
      *(bf16x8*)p = v0;
      *(bf16x8*)&p[8] = v1;
    }
  } else {
    // ---- V^T [B,H,dk,N]: col-major scratch [d64][row16] does the transpose;
    // each lane then stores 32B contiguous in s.
#pragma unroll
    for (int i = 0; i < 4; ++i) {
#pragma unroll
      for (int j = 0; j < 4; ++j) {
        bf16x4 pk;
#pragma unroll
        for (int rr = 0; rr < 4; ++rr) pk[rr] = (__bf16)(acc[i][j][rr] + bj4[j]);
        *(bf16x4*)&scr[(j * 16 + ln15) * 16 + quad * 4] = pk;
      }
      bf16x8 c0 = *(const bf16x8*)&scr[lane * 16];
      bf16x8 c1 = *(const bf16x8*)&scr[lane * 16 + 8];
      __bf16* p = out + (((size_t)(bb * NHEAD + h)) * DKH + lane) * SEQ
                      + s_base + i * 16;
      *(bf16x8*)p = c0;
      *(bf16x8*)&p[8] = c1;
    }
  }
}

// ---------------------------------------------------------------------------
// Output projection: d_out(fp32) = O[M,K]bf16 @ Wo[N,K]bf16^T + bo(fp32).
// 64x128 tile -> 512 blocks (2/CU). 4 waves, each 64 rows x 32 cols.
// ---------------------------------------------------------------------------
__global__ __launch_bounds__(256) void out_gemm(
    const __bf16* __restrict__ A, const __bf16* __restrict__ Wo,
    const float* __restrict__ bo, float* __restrict__ out)
{
  __shared__ __align__(16) __bf16 lds[6144];   // A 64x32 | B 128x32 (12 KB)
  __bf16* A_lds = lds;
  __bf16* B_lds = lds + 2048;

  const int m0 = blockIdx.x * 64;
  const int n0 = blockIdx.y * 128;

  const int t = threadIdx.x, w = t >> 6, lane = t & 63;
  const int ln15 = lane & 15, quad = lane >> 4;

  f32x4 acc[4][2];
#pragma unroll
  for (int i = 0; i < 4; ++i)
#pragma unroll
    for (int j = 0; j < 2; ++j) acc[i][j] = (f32x4){0.f, 0.f, 0.f, 0.f};

  for (int kt = 0; kt < KDIM; kt += 32) {
    __syncthreads();
    {  // A: 64 rows x 4 chunks = 256 chunks = 1 issue
      const int c = (w << 6) + lane;
      const int row = c >> 2;
      const int goff = ((c & 3) ^ (row & 3)) << 3;
      async16(A + (size_t)(m0 + row) * KDIM + kt + goff, A_lds + c * 8);
    }
#pragma unroll
    for (int issue = 0; issue < 2; ++issue) {  // B: 128 rows x 4 chunks = 2 issues
      const int cbase = issue * 256 + (w << 6);
      const int c = cbase + lane;
      const int row = c >> 2;
      const int goff = ((c & 3) ^ (row & 3)) << 3;
      async16(Wo + (size_t)(n0 + row) * KDIM + kt + goff, B_lds + cbase * 8);
    }
    __syncthreads();

    bf16x8 af[4], bfr[2];
#pragma unroll
    for (int i = 0; i < 4; ++i) {
      const int row = i * 16 + ln15;
      af[i] = *(const bf16x8*)&A_lds[row * 32 + ((quad ^ (row & 3)) << 3)];
    }
#pragma unroll
    for (int j = 0; j < 2; ++j) {
      const int row = (w << 5) + j * 16 + ln15;
      bfr[j] = *(const bf16x8*)&B_lds[row * 32 + ((quad ^ (row & 3)) << 3)];
    }
#pragma unroll
    for (int i = 0; i < 4; ++i)
#pragma unroll
      for (int j = 0; j < 2; ++j)
        acc[i][j] = __builtin_amdgcn_mfma_f32_16x16x32_bf16(af[i], bfr[j], acc[i][j], 0, 0, 0);
  }

  float bj2[2];
#pragma unroll
  for (int j = 0; j < 2; ++j) bj2[j] = bo[n0 + (w << 5) + j * 16 + ln15];

  __syncthreads();                          // waves done reading A/B tiles
  float* scrf = (float*)lds + (w << 9);     // per-wave 512-float scratch (2 KB)

  const int rdrow = lane & 15, rdseg = lane >> 4;
#pragma unroll
  for (int i = 0; i < 4; ++i) {
#pragma unroll
    for (int j = 0; j < 2; ++j) {
      f32x4 v;
#pragma unroll
      for (int rr = 0; rr < 4; ++rr) v[rr] = acc[i][j][rr] + bj2[j];
      *(f32x4*)&scrf[(j * 16 + ln15) * 16 + quad * 4] = v;   // col-major
    }
    const int m = m0 + i * 16 + rdrow;
    float* p = out + (size_t)m * DMODEL + n0 + (w << 5) + rdseg * 8;
#pragma unroll
    for (int cc = 0; cc < 2; ++cc) {
      f32x4 v;
#pragma unroll
      for (int e = 0; e < 4; ++e)
        v[e] = scrf[(rdseg * 8 + cc * 4 + e) * 16 + rdrow];
      *(f32x4*)&p[cc * 4] = v;
    }
  }
}

// ---------------------------------------------------------------------------
// Flash attention v6 — 128-key staged tiles + Q/P LDS aliasing.
//  - Per-wave compute body is byte-identical to the verified r10 path, run
//    twice per staged tile (2 x 64-key sub-tiles): staging DMAs, vmcnt
//    drains and barriers per FLOP HALVE again (32 -> 16 drains/block).
//    This lever is validated: r9->r10 halved drains -> 1.33x.
//  - Qs is read once into regs at start, then its 16 KB is reused as the
//    per-wave P buffers (loop-top barrier separates last Q read from first
//    P write). LDS = 16 (Q|P) + 16 (K 128x64) + 16 (V 64x128) = 48 KB ->
//    3 blocks/CU (r10: 49 KB -> 2).
//  - 32x32x16 MFMAs; bare v_exp_f32 exp2; bh-major grid (XCD-local K/V, r9).
//  - r7 lesson: explicit dbuf w/ dynamic index regresses. Single buffer.
//  - SQ_LDS_BANK_CONFLICT ~7M = wave64 b64/b128 multi-pass artifact; ignore.
// ---------------------------------------------------------------------------
__global__ __launch_bounds__(256) void attn_kernel(
    const __bf16* __restrict__ Qb, const __bf16* __restrict__ Kb,
    const __bf16* __restrict__ Vtb, __bf16* __restrict__ Ob)
{
  __shared__ __align__(16) __bf16 QP[128 * 64];       // Q tile, then P bufs
  __shared__ __align__(16) __bf16 Ks[128 * 64];       // [key][dk]
  __shared__ __align__(16) __bf16 Vs[64 * 128];       // [d][key]

  const int t = threadIdx.x, w = t >> 6, lane = t & 63;
  const int ln31 = lane & 31, hl = lane >> 5;
  const int bh = blockIdx.x;                 // b*NHEAD + h  (XCD-locality key)
  const int q0 = blockIdx.y * 128;
  const int b = bh >> 4, h = bh & 15;

  const __bf16* Qg = Qb + (size_t)bh * SEQ * DKH + (size_t)q0 * DKH;
  const __bf16* Kg = Kb + (size_t)bh * SEQ * DKH;
  const __bf16* Vg = Vtb + (size_t)bh * DKH * SEQ;

  // stage Q tile (128x64): 1024 chunks / 256 threads = 4 issues
#pragma unroll
  for (int issue = 0; issue < 4; ++issue) {
    const int cbase = issue * 256 + (w << 6);
    const int c = cbase + lane;
    const int row = c >> 3;                         // 8 chunks per 64-elem row
    const int goff = ((c & 7) ^ (row & 7)) << 3;
    async16(Qg + (size_t)row * DKH + goff, QP + cbase * 8);
  }
  __syncthreads();

  // Q B-fragments for this wave's 32 q-rows (held in regs for whole kernel)
  const int qrow = (w << 5) + ln31;
  bf16x8 qf[4];
#pragma unroll
  for (int ks = 0; ks < 4; ++ks) {
    const int chunk = ((2 * ks + hl) ^ (qrow & 7));
    qf[ks] = *(const bf16x8*)&QP[qrow * 64 + (chunk << 3)];
  }

  float l_lane = 0.f;          // row-sum for q-row `qrow` (lane-private)
  f32x16 o0, o1;               // O[32q][64d]: d-blocks 0/1; this lane: d=db*32+ln31
#pragma unroll
  for (int r = 0; r < 16; ++r) { o0[r] = 0.f; o1[r] = 0.f; }

  __bf16* Pw = QP + w * (32 * 64);   // per-wave P buffer aliases dead Q tile

  for (int kt = 0; kt < SEQ; kt += 128) {
    __syncthreads();   // prior tile's Ks/Vs reads done; iter 0: Q reads done
#pragma unroll
    for (int issue = 0; issue < 4; ++issue) {
      const int cbase = issue * 256 + (w << 6);
      const int c = cbase + lane;
      // K [128 keys][64 dk]: 8 chunks/row
      const int krow = c >> 3;
      const int kgoff = ((c & 7) ^ (krow & 7)) << 3;
      async16(Kg + (size_t)(kt + krow) * DKH + kgoff, Ks + cbase * 8);
      // V [64 d][128 keys]: 16 chunks/row
      const int vrow = c >> 4;
      const int vgoff = ((c & 15) ^ (vrow & 15)) << 3;
      async16(Vg + (size_t)vrow * SEQ + kt + vgoff, Vs + cbase * 8);
    }
    __syncthreads();   // drain (1 per 128 keys, was 1 per 64)

#pragma unroll
    for (int kb2 = 0; kb2 < 2; ++kb2) {     // two 64-key sub-tiles
      // S^T = K Q^T: D[m=key][n=q]; 2 key-blocks of 32, K-dim 64 = 4 ksteps
      f32x16 s0, s1;
#pragma unroll
      for (int r = 0; r < 16; ++r) { s0[r] = 0.f; s1[r] = 0.f; }
#pragma unroll
      for (int ks = 0; ks < 4; ++ks) {
        const int r0 = kb2 * 64 + ln31;        // key row, block 0
        const int r1 = kb2 * 64 + 32 + ln31;   // key row, block 1
        const int c0 = (((2 * ks + hl) ^ (r0 & 7)) << 3);
        const int c1 = (((2 * ks + hl) ^ (r1 & 7)) << 3);
        bf16x8 kf0 = *(const bf16x8*)&Ks[r0 * 64 + c0];
        bf16x8 kf1 = *(const bf16x8*)&Ks[r1 * 64 + c1];
        s0 = __builtin_amdgcn_mfma_f32_32x32x16_bf16(kf0, qf[ks], s0, 0, 0, 0);
        s1 = __builtin_amdgcn_mfma_f32_32x32x16_bf16(kf1, qf[ks], s1, 0, 0, 0);
      }

      // p = 2^s (bare v_exp_f32); accumulate l; pack 4 keys -> b64 writes.
      // reg r of key-block kb: key = kb*32 + (r&3) + 8*(r>>2) + 4*hl
      // P layout: [q=ln31][key 0..63], 16B granule g XOR-swizzled with (q&7).
#pragma unroll
      for (int kb = 0; kb < 2; ++kb) {
        const f32x16& s = kb ? s1 : s0;
#pragma unroll
        for (int rg = 0; rg < 4; ++rg) {
          bf16x4 pk;
#pragma unroll
          for (int rr = 0; rr < 4; ++rr) {
            const float pv = __builtin_amdgcn_exp2f(s[rg * 4 + rr]);
            l_lane += pv;
            pk[rr] = (__bf16)pv;
          }
          const int g = kb * 4 + rg;                        // 16B granule
          *(bf16x4*)&Pw[ln31 * 64 + ((g ^ (ln31 & 7)) << 3) + hl * 4] = pk;
        }
      }
      // (no barrier: Pw is wave-private; compiler orders via lgkmcnt)

      // O += P V: A=P[q][key], B=Vs[d][kb2*64+key] rows as B-frags
#pragma unroll
      for (int ks = 0; ks < 4; ++ks) {
        const int pg = (2 * ks + hl) ^ (ln31 & 7);
        bf16x8 pf = *(const bf16x8*)&Pw[ln31 * 64 + (pg << 3)];
        const int vchunk = kb2 * 8 + 2 * ks + hl;           // of 16 chunks
        const int v0 = ln31;            // d row, block 0
        const int v1 = 32 + ln31;       // d row, block 1
        bf16x8 vf0 = *(const bf16x8*)&Vs[v0 * 128 + ((vchunk ^ (v0 & 15)) << 3)];
        bf16x8 vf1 = *(const bf16x8*)&Vs[v1 * 128 + ((vchunk ^ (v1 & 15)) << 3)];
        o0 = __builtin_amdgcn_mfma_f32_32x32x16_bf16(pf, vf0, o0, 0, 0, 0);
        o1 = __builtin_amdgcn_mfma_f32_32x32x16_bf16(pf, vf1, o1, 0, 0, 0);
      }
    }
  }

  // l: both half-waves hold partials of the same q-row -> one xor-32 add
  l_lane += __shfl_xor(l_lane, 32);
  const float inv = 1.0f / l_lane;   // inv for q-row `qrow`, held by this lane

  // epilogue: O[b, q, h*64+d]; lane = d col, q from regs; fetch inv via shfl
#pragma unroll
  for (int r = 0; r < 16; ++r) {
    const int qi = (r & 3) + 8 * (r >> 2) + 4 * hl;    // q within wave's 32
    const float iq = __shfl(inv, qi);                  // from lane qi (hl=0 half)
    const int q = q0 + (w << 5) + qi;
    __bf16* rowp = Ob + ((size_t)(b * SEQ + q)) * DMODEL + h * DKH;
    rowp[ln31]      = (__bf16)(o0[r] * iq);
    rowp[32 + ln31] = (__bf16)(o1[r] * iq);
  }
}

// ---------------------------------------------------------------------------
extern "C" void kernel_launch(void* const* d_in, const int* in_sizes, int n_in,
                              void* d_out, int out_size, void* d_ws, size_t ws_size,
                              hipStream_t stream)
{
  const float* x  = (const float*)d_in[0];
  const float* Wq = (const float*)d_in[1];
  const float* bq = (const float*)d_in[2];
  const float* Wk = (const float*)d_in[3];
  const float* bk = (const float*)d_in[4];
  const float* Wv = (const float*)d_in[5];
  const float* bv = (const float*)d_in[6];
  const float* Wo = (const float*)d_in[7];
  const float* bo = (const float*)d_in[8];
  float*  out = (float*)d_out;
  __bf16* ws  = (__bf16*)d_ws;

  // fp32 -> bf16 for x and the 4 weight matrices (one launch)
  cvt_fp32_bf16<<<dim3(2048, 5, 1), 256, 0, stream>>>(x, Wq, Wk, Wv, Wo, ws);

  // Q,K,V projections (fused, grid.z picks the matrix)
  qkv_gemm<<<dim3(MTOT / 128, DMODEL / 128, 3), 256, 0, stream>>>(
      ws + XB, ws + WQB, bq, ws + WKB, bk, ws + WVB, bv, ws);

  // flash attention: (bh, q-tile of 128) = 512 blocks x 256 threads
  attn_kernel<<<dim3(BATCH * NHEAD, SEQ / 128), 256, 0, stream>>>(
      ws + QOFF, ws + KOFF, ws + VOFF, ws + OOFF);

  // output projection -> fp32 d_out (64x128 tiles, 512 blocks)
  out_gemm<<<dim3(MTOT / 64, DMODEL / 128), 256, 0, stream>>>(
      ws + OOFF, ws + WOB, bo, out);
}